// Round 7
// baseline (264.179 us; speedup 1.0000x reference)
//
#include <hip/hip_runtime.h>
#include <math.h>

#define NB 32   // batch
#define CB 32   // capsule channels C
#define KC 10   // classes
#define PAD_LRT 260  // floats per lrT row
#define PAD_TP  168  // floats per Tp row

// thread = (mg of 16 m, ij-pair, k-half): 28 b128 reads per thread (8 lrT + 20 c)
__device__ __forceinline__ void tp_stage(const float* __restrict__ lrTp,
                                         const float* __restrict__ cl,
                                         float* __restrict__ Tp, int tid) {
    const int mg  = tid >> 4;
    const int r   = tid & 15;
    const int ij0 = (r & 7) * 2;     // handles ij0, ij0+1
    const int k0  = (r >> 3) * 5;    // handles k0..k0+4
    const float4* lp0 = (const float4*)(lrTp + ij0 * PAD_LRT + mg * 16);
    const float4* lp1 = (const float4*)(lrTp + (ij0 + 1) * PAD_LRT + mg * 16);
    float4 a0 = lp0[0], a1 = lp0[1], a2 = lp0[2], a3 = lp0[3];
    float4 b0 = lp1[0], b1 = lp1[1], b2 = lp1[2], b3 = lp1[3];
    #pragma unroll
    for (int kk = 0; kk < 5; ++kk) {
        const int k = k0 + kk;
        const float4* cp = (const float4*)(cl + k * 256 + mg * 16);
        float4 c0 = cp[0], c1 = cp[1], c2 = cp[2], c3 = cp[3];
        float t0 = 0.f, t1 = 0.f;
        t0 = fmaf(c0.x, a0.x, t0); t1 = fmaf(c0.x, b0.x, t1);
        t0 = fmaf(c0.y, a0.y, t0); t1 = fmaf(c0.y, b0.y, t1);
        t0 = fmaf(c0.z, a0.z, t0); t1 = fmaf(c0.z, b0.z, t1);
        t0 = fmaf(c0.w, a0.w, t0); t1 = fmaf(c0.w, b0.w, t1);
        t0 = fmaf(c1.x, a1.x, t0); t1 = fmaf(c1.x, b1.x, t1);
        t0 = fmaf(c1.y, a1.y, t0); t1 = fmaf(c1.y, b1.y, t1);
        t0 = fmaf(c1.z, a1.z, t0); t1 = fmaf(c1.z, b1.z, t1);
        t0 = fmaf(c1.w, a1.w, t0); t1 = fmaf(c1.w, b1.w, t1);
        t0 = fmaf(c2.x, a2.x, t0); t1 = fmaf(c2.x, b2.x, t1);
        t0 = fmaf(c2.y, a2.y, t0); t1 = fmaf(c2.y, b2.y, t1);
        t0 = fmaf(c2.z, a2.z, t0); t1 = fmaf(c2.z, b2.z, t1);
        t0 = fmaf(c2.w, a2.w, t0); t1 = fmaf(c2.w, b2.w, t1);
        t0 = fmaf(c3.x, a3.x, t0); t1 = fmaf(c3.x, b3.x, t1);
        t0 = fmaf(c3.y, a3.y, t0); t1 = fmaf(c3.y, b3.y, t1);
        t0 = fmaf(c3.z, a3.z, t0); t1 = fmaf(c3.z, b3.z, t1);
        t0 = fmaf(c3.w, a3.w, t0); t1 = fmaf(c3.w, b3.w, t1);
        Tp[mg * PAD_TP + k * 16 + ij0]     = t0;
        Tp[mg * PAD_TP + k * 16 + ij0 + 1] = t1;
    }
}

// One routing iteration. mode 0: E computed in-block from g (aeff = g).
// mode 1/2: E read from E_g (written by previous kernel's epilogue).
// Epilogue (last block per n): reduce s-partials -> squash;
//   mode 0/1: update aeff_g, write E_g for next iter; mode 2: write final out.
__global__ __launch_bounds__(256, 4) void caps_iter(
    const float* __restrict__ l,      // (N,C,16,16,16)
    const float* __restrict__ g,      // (N,10,16)
    const float* __restrict__ weight, // (C,10,4,4)
    float* __restrict__ s_part,       // (N*C,160)
    float* __restrict__ E_g,          // (N*C,160)
    float* __restrict__ aeff_g,       // (N,160)
    int* __restrict__ ctr,            // (N) zeroed before this kernel
    float* __restrict__ out,          // [a(320)|v(5120)], mode 2 only
    int mode)
{
    __shared__ __align__(16) float w_lds[160];
    __shared__ __align__(16) float E_lds[160];
    __shared__ __align__(16) float aeff_lds[160];
    __shared__ __align__(16) float lrT[16 * PAD_LRT];
    __shared__ __align__(16) float c_lds[KC * 256];
    __shared__ __align__(16) float Tp[16 * PAD_TP];
    __shared__ __align__(16) float T_lds[160];
    __shared__ int lastflag;

    const int tid = threadIdx.x;
    const int bid = blockIdx.x;
    const int n = bid >> 5;
    const int c = bid & 31;

    if (tid < 160) w_lds[tid] = weight[c * 160 + tid];

    // per-thread pose (coalesced) + transposed LDS copy
    float lr[16];
    const float* lbase = l + (size_t)bid * 4096 + tid;
    #pragma unroll
    for (int ij = 0; ij < 16; ++ij) lr[ij] = lbase[ij * 256];
    #pragma unroll
    for (int ij = 0; ij < 16; ++ij) lrT[ij * PAD_LRT + tid] = lr[ij];

    float b[KC];
    if (mode == 0) {
        // aeff = g; E in-block
        if (tid < 160) aeff_lds[tid] = g[n * 160 + tid];
        __syncthreads();                                // S0: w, lrT, aeff
        if (tid < 160) {
            const int k = tid >> 4, i = (tid >> 2) & 3, j = tid & 3;
            const float4 a4 = *(const float4*)(aeff_lds + k * 16 + i * 4);
            const float4 w4 = *(const float4*)(w_lds + k * 16 + j * 4);
            E_lds[tid] = a4.x * w4.x + a4.y * w4.y + a4.z * w4.z + a4.w * w4.w;
        }
        __syncthreads();                                // S1: E ready
        #pragma unroll
        for (int k = 0; k < KC; ++k) {
            const float4* e4 = (const float4*)(E_lds + k * 16);
            float4 e0 = e4[0], e1 = e4[1], e2 = e4[2], e3 = e4[3];
            float acc = 0.f;
            acc = fmaf(lr[0], e0.x, acc);  acc = fmaf(lr[1], e0.y, acc);
            acc = fmaf(lr[2], e0.z, acc);  acc = fmaf(lr[3], e0.w, acc);
            acc = fmaf(lr[4], e1.x, acc);  acc = fmaf(lr[5], e1.y, acc);
            acc = fmaf(lr[6], e1.z, acc);  acc = fmaf(lr[7], e1.w, acc);
            acc = fmaf(lr[8], e2.x, acc);  acc = fmaf(lr[9], e2.y, acc);
            acc = fmaf(lr[10], e2.z, acc); acc = fmaf(lr[11], e2.w, acc);
            acc = fmaf(lr[12], e3.x, acc); acc = fmaf(lr[13], e3.y, acc);
            acc = fmaf(lr[14], e3.z, acc); acc = fmaf(lr[15], e3.w, acc);
            b[k] = acc;
        }
    } else {
        __syncthreads();                                // S0: w, lrT ready
        // E from global via uniform (scalarizable) pointer
        const float4* Eg = (const float4*)(E_g + (size_t)bid * 160);
        #pragma unroll
        for (int k = 0; k < KC; ++k) {
            float4 e0 = Eg[k * 4 + 0], e1 = Eg[k * 4 + 1];
            float4 e2 = Eg[k * 4 + 2], e3 = Eg[k * 4 + 3];
            float acc = 0.f;
            acc = fmaf(lr[0], e0.x, acc);  acc = fmaf(lr[1], e0.y, acc);
            acc = fmaf(lr[2], e0.z, acc);  acc = fmaf(lr[3], e0.w, acc);
            acc = fmaf(lr[4], e1.x, acc);  acc = fmaf(lr[5], e1.y, acc);
            acc = fmaf(lr[6], e1.z, acc);  acc = fmaf(lr[7], e1.w, acc);
            acc = fmaf(lr[8], e2.x, acc);  acc = fmaf(lr[9], e2.y, acc);
            acc = fmaf(lr[10], e2.z, acc); acc = fmaf(lr[11], e2.w, acc);
            acc = fmaf(lr[12], e3.x, acc); acc = fmaf(lr[13], e3.y, acc);
            acc = fmaf(lr[14], e3.z, acc); acc = fmaf(lr[15], e3.w, acc);
            b[k] = acc;
        }
    }

    // softmax over k -> c_lds[k][m=tid]
    {
        float mx = b[0];
        #pragma unroll
        for (int k = 1; k < KC; ++k) mx = fmaxf(mx, b[k]);
        float sum = 0.f;
        #pragma unroll
        for (int k = 0; k < KC; ++k) { b[k] = __expf(b[k] - mx); sum += b[k]; }
        const float inv = 1.f / sum;
        #pragma unroll
        for (int k = 0; k < KC; ++k) c_lds[k * 256 + tid] = b[k] * inv;
    }
    __syncthreads();                                    // S2: c ready

    tp_stage(lrT, c_lds, Tp, tid);
    __syncthreads();                                    // S3: Tp ready

    if (tid < 160) {
        float t = 0.f;
        #pragma unroll
        for (int mg = 0; mg < 16; ++mg) t += Tp[mg * PAD_TP + tid];
        T_lds[tid] = t;
    }
    __syncthreads();                                    // S4: T ready

    // s_part[bid][tid] = sum_j T[k][i*4+j] * w[k][j*4+le]
    if (tid < 160) {
        const int k = tid >> 4;
        const int i = (tid >> 2) & 3;
        const int le = tid & 3;
        const float4 t4 = *(const float4*)(T_lds + k * 16 + i * 4);
        float sv = 0.f;
        sv = fmaf(t4.x, w_lds[k * 16 + 0 + le], sv);
        sv = fmaf(t4.y, w_lds[k * 16 + 4 + le], sv);
        sv = fmaf(t4.z, w_lds[k * 16 + 8 + le], sv);
        sv = fmaf(t4.w, w_lds[k * 16 + 12 + le], sv);
        s_part[(size_t)bid * 160 + tid] = sv;
    }

    // ---- last-block-per-n epilogue (no spin: last arrival does the work) ----
    __threadfence();                                    // release s_part write
    if (tid == 0) {
        const int old = atomicAdd(&ctr[n], 1);
        lastflag = (old == CB - 1);
    }
    __syncthreads();
    if (!lastflag) return;
    __threadfence();                                    // acquire all partials

    float ssum = 0.f;
    if (tid < 160) {
        const float* sp = s_part + (size_t)n * (CB * 160) + tid;
        #pragma unroll
        for (int c2 = 0; c2 < CB; ++c2)
            ssum += __hip_atomic_load(sp + c2 * 160, __ATOMIC_RELAXED,
                                      __HIP_MEMORY_SCOPE_AGENT);
    }
    float sq = ssum * ssum;
    sq += __shfl_xor(sq, 1, 16);
    sq += __shfl_xor(sq, 2, 16);
    sq += __shfl_xor(sq, 4, 16);
    sq += __shfl_xor(sq, 8, 16);
    sq = fmaxf(sq, 1e-30f);
    const float vterm = ssum * sq / ((1.f + sq) * sqrtf(sq));  // squashed component

    if (mode < 2) {
        // aeff_{next} = (mode==0 ? g : aeff_prev) + v; write E_{next}[c] for all c
        if (tid < 160) {
            const float an = (mode == 0 ? g[n * 160 + tid] : aeff_g[n * 160 + tid]) + vterm;
            aeff_g[n * 160 + tid] = an;
            aeff_lds[tid] = an;
        }
        __syncthreads();
        if (tid < 160) {
            const int k = tid >> 4, i = (tid >> 2) & 3, j = tid & 3;
            const float4 a4 = *(const float4*)(aeff_lds + k * 16 + i * 4);
            float* Eo = E_g + (size_t)n * (CB * 160) + tid;
            #pragma unroll 4
            for (int c2 = 0; c2 < CB; ++c2) {
                const float4 w4 = *(const float4*)(weight + c2 * 160 + k * 16 + j * 4);
                Eo[c2 * 160] = a4.x * w4.x + a4.y * w4.y + a4.z * w4.z + a4.w * w4.w;
            }
        }
    } else {
        // final output: v = vterm; a = sigmoid(||v||) = sigmoid(sq/(1+sq))
        if (tid < 160) {
            const int k = tid >> 4, d = tid & 15;
            out[320 + (n * KC + k) * 16 + d] = vterm;
            if (d == 0) {
                const float nrm = sq / (1.f + sq);
                out[n * KC + k] = 1.f / (1.f + __expf(-nrm));
            }
        }
    }
}

extern "C" void kernel_launch(void* const* d_in, const int* in_sizes, int n_in,
                              void* d_out, int out_size, void* d_ws, size_t ws_size,
                              hipStream_t stream) {
    const float* l = (const float*)d_in[0];
    const float* g = (const float*)d_in[1];
    const float* w = (const float*)d_in[2];
    float* out = (float*)d_out;
    float* ws = (float*)d_ws;

    float* s_part = ws;                 // 163840 floats
    float* E_g    = ws + 163840;        // 163840 floats
    float* aeff_g = ws + 327680;        // 5120 floats
    int*   ctr    = (int*)(ws + 332800); // 3*32 ints

    hipMemsetAsync(ctr, 0, 3 * NB * sizeof(int), stream);

    caps_iter<<<dim3(NB * CB), dim3(256), 0, stream>>>(
        l, g, w, s_part, E_g, aeff_g, ctr + 0 * NB, out, 0);
    caps_iter<<<dim3(NB * CB), dim3(256), 0, stream>>>(
        l, g, w, s_part, E_g, aeff_g, ctr + 1 * NB, out, 1);
    caps_iter<<<dim3(NB * CB), dim3(256), 0, stream>>>(
        l, g, w, s_part, E_g, aeff_g, ctr + 2 * NB, out, 2);
}

// Round 8
// 29.123 us; speedup vs baseline: 9.0712x; 9.0712x over previous
//
#include <hip/hip_runtime.h>
#include <math.h>

#define NB 32   // batch
#define CB 32   // capsule channels C
#define KC 10   // classes
#define PAD_LRT 260  // floats per lrT row
#define PAD_TP  168  // floats per Tp row

// s_part layout: s[n][c][160] (block-contiguous writes, lane-coalesced c-reduction reads)

// sum over c of s_part[n][c][tid] followed by squash scaling for this (k,d); tid<160
__device__ __forceinline__ float squash_term(const float* __restrict__ sp, int n, int tid) {
    const float* p = sp + (size_t)n * (CB * 160) + tid;
    float t0 = 0.f, t1 = 0.f, t2 = 0.f, t3 = 0.f;
    #pragma unroll
    for (int cc = 0; cc < 32; cc += 4) {
        t0 += p[cc * 160];       t1 += p[(cc + 1) * 160];
        t2 += p[(cc + 2) * 160]; t3 += p[(cc + 3) * 160];
    }
    float ssum = (t0 + t1) + (t2 + t3);
    float sq = ssum * ssum;
    sq += __shfl_xor(sq, 1, 16);
    sq += __shfl_xor(sq, 2, 16);
    sq += __shfl_xor(sq, 4, 16);
    sq += __shfl_xor(sq, 8, 16);
    sq = fmaxf(sq, 1e-30f);
    return ssum * sq / ((1.f + sq) * sqrtf(sq));
}

// b = lr.E, softmax over k, write c row-major [k][m=tid]
__device__ __forceinline__ void softmax_c(const float lr[16], const float* __restrict__ E,
                                          float* __restrict__ c_out, int tid) {
    float b[KC];
    #pragma unroll
    for (int k = 0; k < KC; ++k) {
        const float4* e4 = (const float4*)(E + k * 16);
        float4 e0 = e4[0], e1 = e4[1], e2 = e4[2], e3 = e4[3];
        float acc = 0.f;
        acc = fmaf(lr[0], e0.x, acc);  acc = fmaf(lr[1], e0.y, acc);
        acc = fmaf(lr[2], e0.z, acc);  acc = fmaf(lr[3], e0.w, acc);
        acc = fmaf(lr[4], e1.x, acc);  acc = fmaf(lr[5], e1.y, acc);
        acc = fmaf(lr[6], e1.z, acc);  acc = fmaf(lr[7], e1.w, acc);
        acc = fmaf(lr[8], e2.x, acc);  acc = fmaf(lr[9], e2.y, acc);
        acc = fmaf(lr[10], e2.z, acc); acc = fmaf(lr[11], e2.w, acc);
        acc = fmaf(lr[12], e3.x, acc); acc = fmaf(lr[13], e3.y, acc);
        acc = fmaf(lr[14], e3.z, acc); acc = fmaf(lr[15], e3.w, acc);
        b[k] = acc;
    }
    float mx = b[0];
    #pragma unroll
    for (int k = 1; k < KC; ++k) mx = fmaxf(mx, b[k]);
    float sum = 0.f;
    #pragma unroll
    for (int k = 0; k < KC; ++k) { b[k] = __expf(b[k] - mx); sum += b[k]; }
    const float inv = 1.f / sum;
    #pragma unroll
    for (int k = 0; k < KC; ++k) c_out[k * 256 + tid] = b[k] * inv;
}

// thread = (mg of 16 m, ij & ij+8, k-half): 28 b128 reads/thread (8 lrT + 20 c).
// ij split {r&7, (r&7)+8} spreads lrT read start-banks over 8 (vs 4 with {2r,2r+1}).
__device__ __forceinline__ void tp_stage(const float* __restrict__ lrTp,
                                         const float* __restrict__ cl,
                                         float* __restrict__ Tp, int tid) {
    const int mg  = tid >> 4;
    const int r   = tid & 15;
    const int ija = r & 7;           // handles ija and ija+8
    const int ijb = ija + 8;
    const int k0  = (r >> 3) * 5;    // handles k0..k0+4
    const float4* lp0 = (const float4*)(lrTp + ija * PAD_LRT + mg * 16);
    const float4* lp1 = (const float4*)(lrTp + ijb * PAD_LRT + mg * 16);
    float4 a0 = lp0[0], a1 = lp0[1], a2 = lp0[2], a3 = lp0[3];
    float4 b0 = lp1[0], b1 = lp1[1], b2 = lp1[2], b3 = lp1[3];
    #pragma unroll
    for (int kk = 0; kk < 5; ++kk) {
        const int k = k0 + kk;
        const float4* cp = (const float4*)(cl + k * 256 + mg * 16);
        float4 c0 = cp[0], c1 = cp[1], c2 = cp[2], c3 = cp[3];
        float t0 = 0.f, t1 = 0.f;
        t0 = fmaf(c0.x, a0.x, t0); t1 = fmaf(c0.x, b0.x, t1);
        t0 = fmaf(c0.y, a0.y, t0); t1 = fmaf(c0.y, b0.y, t1);
        t0 = fmaf(c0.z, a0.z, t0); t1 = fmaf(c0.z, b0.z, t1);
        t0 = fmaf(c0.w, a0.w, t0); t1 = fmaf(c0.w, b0.w, t1);
        t0 = fmaf(c1.x, a1.x, t0); t1 = fmaf(c1.x, b1.x, t1);
        t0 = fmaf(c1.y, a1.y, t0); t1 = fmaf(c1.y, b1.y, t1);
        t0 = fmaf(c1.z, a1.z, t0); t1 = fmaf(c1.z, b1.z, t1);
        t0 = fmaf(c1.w, a1.w, t0); t1 = fmaf(c1.w, b1.w, t1);
        t0 = fmaf(c2.x, a2.x, t0); t1 = fmaf(c2.x, b2.x, t1);
        t0 = fmaf(c2.y, a2.y, t0); t1 = fmaf(c2.y, b2.y, t1);
        t0 = fmaf(c2.z, a2.z, t0); t1 = fmaf(c2.z, b2.z, t1);
        t0 = fmaf(c2.w, a2.w, t0); t1 = fmaf(c2.w, b2.w, t1);
        t0 = fmaf(c3.x, a3.x, t0); t1 = fmaf(c3.x, b3.x, t1);
        t0 = fmaf(c3.y, a3.y, t0); t1 = fmaf(c3.y, b3.y, t1);
        t0 = fmaf(c3.z, a3.z, t0); t1 = fmaf(c3.z, b3.z, t1);
        t0 = fmaf(c3.w, a3.w, t0); t1 = fmaf(c3.w, b3.w, t1);
        Tp[mg * PAD_TP + k * 16 + ija] = t0;
        Tp[mg * PAD_TP + k * 16 + ijb] = t1;
    }
}

__device__ __forceinline__ void t_reduce(const float* __restrict__ Tp,
                                         float* __restrict__ T, int tid) {
    if (tid < 160) {
        float t = 0.f;
        #pragma unroll
        for (int mg = 0; mg < 16; ++mg) t += Tp[mg * PAD_TP + tid];
        T[tid] = t;
    }
}

// s_part[k][i][le] = sum_j T[k][i*4+j] * w[k][j*4+le]
__device__ __forceinline__ void s_write(const float* __restrict__ T,
                                        const float* __restrict__ w,
                                        float* __restrict__ s_base, int tid) {
    if (tid < 160) {
        const int k = tid >> 4;
        const int i = (tid >> 2) & 3;
        const int le = tid & 3;
        const float4 t4 = *(const float4*)(T + k * 16 + i * 4);
        float sv = 0.f;
        sv = fmaf(t4.x, w[k * 16 + 0 + le], sv);
        sv = fmaf(t4.y, w[k * 16 + 4 + le], sv);
        sv = fmaf(t4.z, w[k * 16 + 8 + le], sv);
        sv = fmaf(t4.w, w[k * 16 + 12 + le], sv);
        s_base[tid] = sv;
    }
}

__global__ __launch_bounds__(256) void caps_main(
    const float* __restrict__ l, const float* __restrict__ g,
    const float* __restrict__ weight,
    const float* __restrict__ sp0, const float* __restrict__ sp1,
    float* __restrict__ s_out, int nv)
{
    __shared__ __align__(16) float w_lds[160];
    __shared__ __align__(16) float aeff_lds[160];
    __shared__ __align__(16) float E_lds[160];
    __shared__ __align__(16) float lrT[16 * PAD_LRT];
    __shared__ __align__(16) float c_lds[KC * 256];
    __shared__ __align__(16) float Tp[16 * PAD_TP];
    __shared__ __align__(16) float T_lds[160];

    const int tid = threadIdx.x;
    const int n = blockIdx.x >> 5;
    const int c = blockIdx.x & 31;

    if (tid < 160) w_lds[tid] = weight[c * 160 + tid];

    // per-thread pose (coalesced 256B/wave-inst) + transposed LDS copy
    float lr[16];
    const float* lbase = l + (size_t)(n * CB + c) * 4096 + tid;
    #pragma unroll
    for (int ij = 0; ij < 16; ++ij) lr[ij] = lbase[ij * 256];
    #pragma unroll
    for (int ij = 0; ij < 16; ++ij) lrT[ij * PAD_LRT + tid] = lr[ij];

    if (tid < 160) {
        float a = g[n * 160 + tid];
        if (nv > 0) a += squash_term(sp0, n, tid);
        if (nv > 1) a += squash_term(sp1, n, tid);
        aeff_lds[tid] = a;
    }
    __syncthreads();                                    // S1: w, lrT, aeff ready

    if (tid < 160) {
        const int k = tid >> 4, i = (tid >> 2) & 3, j = tid & 3;
        const float4 a4 = *(const float4*)(aeff_lds + k * 16 + i * 4);
        const float4 w4 = *(const float4*)(w_lds + k * 16 + j * 4);
        E_lds[tid] = a4.x * w4.x + a4.y * w4.y + a4.z * w4.z + a4.w * w4.w;
    }
    __syncthreads();                                    // S2: E ready

    softmax_c(lr, E_lds, c_lds, tid);
    __syncthreads();                                    // S3: c ready
    tp_stage(lrT, c_lds, Tp, tid);
    __syncthreads();                                    // S4: Tp ready
    t_reduce(Tp, T_lds, tid);
    __syncthreads();                                    // S5: T ready
    s_write(T_lds, w_lds, s_out + (size_t)blockIdx.x * 160, tid);
}

// final: v = squash(sum_c s2), a = sigmoid(||v||); out = [a(320) | v(5120)]
__global__ __launch_bounds__(256) void caps_final(
    const float* __restrict__ sp2, float* __restrict__ out)
{
    const int idx = blockIdx.x * 256 + threadIdx.x;  // 0..5119
    const int nk = idx >> 4;
    const int d = idx & 15;
    const int n = nk / 10;
    const int k = nk - n * 10;
    const float* sp = sp2 + (size_t)n * (CB * 160) + k * 16 + d;
    float t0 = 0.f, t1 = 0.f, t2 = 0.f, t3 = 0.f;
    #pragma unroll
    for (int cc = 0; cc < 32; cc += 4) {
        t0 += sp[cc * 160];       t1 += sp[(cc + 1) * 160];
        t2 += sp[(cc + 2) * 160]; t3 += sp[(cc + 3) * 160];
    }
    float ssum = (t0 + t1) + (t2 + t3);
    float sq = ssum * ssum;
    sq += __shfl_xor(sq, 1, 16);
    sq += __shfl_xor(sq, 2, 16);
    sq += __shfl_xor(sq, 4, 16);
    sq += __shfl_xor(sq, 8, 16);
    sq = fmaxf(sq, 1e-30f);
    out[320 + nk * 16 + d] = ssum * sq / ((1.f + sq) * sqrtf(sq));
    if (d == 0) {
        const float nrm = sq / (1.f + sq);   // == ||v||
        out[nk] = 1.f / (1.f + __expf(-nrm));
    }
}

extern "C" void kernel_launch(void* const* d_in, const int* in_sizes, int n_in,
                              void* d_out, int out_size, void* d_ws, size_t ws_size,
                              hipStream_t stream) {
    const float* l = (const float*)d_in[0];
    const float* g = (const float*)d_in[1];
    const float* w = (const float*)d_in[2];
    float* out = (float*)d_out;
    float* ws = (float*)d_ws;

    float* s0 = ws;                 // (N,C,160) = 163840 floats each
    float* s1 = ws + 163840;
    float* s2 = ws + 327680;

    caps_main<<<dim3(NB * CB), dim3(256), 0, stream>>>(l, g, w, nullptr, nullptr, s0, 0);
    caps_main<<<dim3(NB * CB), dim3(256), 0, stream>>>(l, g, w, s0, nullptr, s1, 1);
    caps_main<<<dim3(NB * CB), dim3(256), 0, stream>>>(l, g, w, s0, s1, s2, 2);
    caps_final<<<dim3(20), dim3(256), 0, stream>>>(s2, out);
}